// Round 1
// baseline (133.944 us; speedup 1.0000x reference)
//
#include <hip/hip_runtime.h>
#include <math.h>

typedef unsigned short u16;
typedef unsigned int u32;
typedef __attribute__((ext_vector_type(8))) __bf16 bf16x8;
typedef __attribute__((ext_vector_type(4))) float f32x4;

#define BM 128
#define BN 128
#define BK 64

// ---------- helpers ----------

__device__ __forceinline__ u16 f2bf(float x) {
    __bf16 h = (__bf16)x;                 // fptrunc = round-to-nearest-even
    return __builtin_bit_cast(u16, h);
}

// order-preserving float -> uint mapping (monotonic), for atomicMax on floats
__device__ __forceinline__ u32 ordf(float f) {
    u32 u = __float_as_uint(f);
    return (u & 0x80000000u) ? ~u : (u | 0x80000000u);
}
__device__ __forceinline__ float unordf(u32 u) {
    u = (u & 0x80000000u) ? (u & 0x7FFFFFFFu) : ~u;
    return __uint_as_float(u);
}

// async global->LDS, 16B per lane (dest = wave-uniform base + lane*16)
__device__ __forceinline__ void gload_lds16(const void* gsrc, void* ldst) {
    __builtin_amdgcn_global_load_lds(
        (const __attribute__((address_space(1))) void*)gsrc,
        (__attribute__((address_space(3))) void*)ldst,
        16, 0, 0);
}

// ---------- kernel 1: normalize rows, convert to bf16; init rowmax ----------
// one wave per row; lane handles 8 consecutive floats (D=512 = 64 lanes * 8)

__global__ __launch_bounds__(256) void norm_kernel(
    const float* __restrict__ feat, const float* __restrict__ memf,
    u16* __restrict__ fb, u16* __restrict__ mb, u32* __restrict__ rowmax,
    int N, int M, int D)
{
    const int lane = threadIdx.x & 63;
    const int wid  = threadIdx.x >> 6;
    const int rid  = blockIdx.x * 4 + wid;
    if (rid >= N + M) return;

    const float* src;
    u16* dst;
    if (rid < N) { src = feat + (size_t)rid * D; dst = fb + (size_t)rid * D; }
    else         { src = memf + (size_t)(rid - N) * D; dst = mb + (size_t)(rid - N) * D; }

    float4 v0 = *(const float4*)(src + lane * 8);
    float4 v1 = *(const float4*)(src + lane * 8 + 4);
    float ss = v0.x*v0.x + v0.y*v0.y + v0.z*v0.z + v0.w*v0.w
             + v1.x*v1.x + v1.y*v1.y + v1.z*v1.z + v1.w*v1.w;
    #pragma unroll
    for (int m = 1; m <= 32; m <<= 1) ss += __shfl_xor(ss, m);

    float nrm = fmaxf(sqrtf(ss), 1e-8f);
    float inv = 1.0f / nrm;

    u16 o[8];
    o[0] = f2bf(v0.x * inv); o[1] = f2bf(v0.y * inv);
    o[2] = f2bf(v0.z * inv); o[3] = f2bf(v0.w * inv);
    o[4] = f2bf(v1.x * inv); o[5] = f2bf(v1.y * inv);
    o[6] = f2bf(v1.z * inv); o[7] = f2bf(v1.w * inv);
    *(uint4*)(dst + lane * 8) = *(const uint4*)o;

    if (rid < N && lane == 0) rowmax[rid] = 0u;   // ordered(-NaN): below any real sim
}

// ---------- kernel 2: C = Fn @ Mnᵀ tile, fused row-max ----------
// 128x128 tile, BK=64, 4 waves (2x2), each wave 64x64 = 4x4 fragments of 16x16x32.
// LDS image XOR-swizzled: image[row][kb ^ ((row&7)<<4)] = tile[row][kb]
// (achieved by pre-swizzling the GLOBAL source chunk; LDS dest stays linear).

__global__ __launch_bounds__(256) void gemm_max_kernel(
    const u16* __restrict__ fb, const u16* __restrict__ mb,
    u32* __restrict__ rowmax, int N, int M, int D)
{
    __shared__ __align__(16) u16 As[BM * BK];
    __shared__ __align__(16) u16 Bs[BN * BK];

    const int tid  = threadIdx.x;
    const int lane = tid & 63;
    const int wid  = tid >> 6;
    const int wr   = wid >> 1;       // wave row (0..1)
    const int wc   = wid & 1;        // wave col (0..1)
    const int l15  = lane & 15;
    const int l4   = lane >> 4;
    const int n0   = blockIdx.y * BM;
    const int m0   = blockIdx.x * BN;

    f32x4 acc[4][4] = {};

    for (int k0 = 0; k0 < D; k0 += BK) {
        __syncthreads();   // previous compute done before overwriting LDS
        // stage A and B tiles (16KB each): 4 iters x 256 threads x 16B
        #pragma unroll
        for (int i = 0; i < 4; ++i) {
            int r = i * 32 + (tid >> 3);           // tile row
            int c = (tid & 7) ^ (r & 7);           // pre-swizzled source chunk
            gload_lds16(fb + (size_t)(n0 + r) * D + k0 + c * 8, &As[(i * 256 + tid) * 8]);
            gload_lds16(mb + (size_t)(m0 + r) * D + k0 + c * 8, &Bs[(i * 256 + tid) * 8]);
        }
        __syncthreads();   // drains vmcnt before barrier

        #pragma unroll
        for (int ks = 0; ks < 2; ++ks) {
            bf16x8 a[4], b[4];
            const int kb = ks * 64 + l4 * 16;      // byte offset within 128B row
            #pragma unroll
            for (int i = 0; i < 4; ++i) {
                int ra = wr * 64 + i * 16 + l15;
                a[i] = *(const bf16x8*)((const char*)As + ra * 128 + (kb ^ ((ra & 7) << 4)));
                int rb = wc * 64 + i * 16 + l15;
                b[i] = *(const bf16x8*)((const char*)Bs + rb * 128 + (kb ^ ((rb & 7) << 4)));
            }
            #pragma unroll
            for (int i = 0; i < 4; ++i)
                #pragma unroll
                for (int j = 0; j < 4; ++j)
                    acc[i][j] = __builtin_amdgcn_mfma_f32_16x16x32_bf16(a[i], b[j], acc[i][j], 0, 0, 0);
        }
    }

    // epilogue: per-row max over this wave's 64 columns, then global atomicMax
    // acc[i][j][r]: row = n0 + wr*64 + i*16 + l4*4 + r ; col = m0 + wc*64 + j*16 + l15
    #pragma unroll
    for (int i = 0; i < 4; ++i) {
        #pragma unroll
        for (int r = 0; r < 4; ++r) {
            float v = fmaxf(fmaxf(acc[i][0][r], acc[i][1][r]),
                            fmaxf(acc[i][2][r], acc[i][3][r]));
            v = fmaxf(v, __shfl_xor(v, 1));
            v = fmaxf(v, __shfl_xor(v, 2));
            v = fmaxf(v, __shfl_xor(v, 4));
            v = fmaxf(v, __shfl_xor(v, 8));
            if (l15 == 0) {
                int row = n0 + wr * 64 + i * 16 + l4 * 4 + r;
                atomicMax(&rowmax[row], ordf(v));
            }
        }
    }
}

// ---------- kernel 3: BCE + novelty weight + mean ----------

__global__ __launch_bounds__(1024) void finalize_kernel(
    const float* __restrict__ pred, const float* __restrict__ targ,
    const u32* __restrict__ rowmax, float* __restrict__ out, int N)
{
    __shared__ float wsum[16];
    const int tid = threadIdx.x;
    const int lane = tid & 63;
    const int wid = tid >> 6;

    float s = 0.f;
    for (int i = tid; i < N; i += 1024) {
        float x = pred[i];
        float t = targ[i];
        float bl = fmaxf(x, 0.f) + log1pf(expf(-fabsf(x))) - x * t;  // softplus(x) - x*t
        float ms = unordf(rowmax[i]);
        float w = 1.0f + 2.0f * (1.0f - ms);
        s += bl * w;
    }
    #pragma unroll
    for (int m = 1; m <= 32; m <<= 1) s += __shfl_xor(s, m);
    if (lane == 0) wsum[wid] = s;
    __syncthreads();
    if (tid < 16) {
        float t = wsum[tid];
        t += __shfl_xor(t, 1);
        t += __shfl_xor(t, 2);
        t += __shfl_xor(t, 4);
        t += __shfl_xor(t, 8);
        if (tid == 0) out[0] = t / (float)N;
    }
}

// ---------- launch ----------

extern "C" void kernel_launch(void* const* d_in, const int* in_sizes, int n_in,
                              void* d_out, int out_size, void* d_ws, size_t ws_size,
                              hipStream_t stream) {
    const float* pred = (const float*)d_in[0];
    const float* targ = (const float*)d_in[1];
    const float* feat = (const float*)d_in[2];
    const float* memf = (const float*)d_in[3];
    const int N = in_sizes[0];
    const int D = in_sizes[2] / N;
    const int M = in_sizes[3] / D;
    float* out = (float*)d_out;

    u16* fb = (u16*)d_ws;                          // N*D bf16
    u16* mb = fb + (size_t)N * D;                  // M*D bf16
    u32* rowmax = (u32*)(mb + (size_t)M * D);      // N u32

    const int rows = N + M;
    norm_kernel<<<dim3((rows + 3) / 4), dim3(256), 0, stream>>>(
        feat, memf, fb, mb, rowmax, N, M, D);
    gemm_max_kernel<<<dim3(M / BN, N / BM), dim3(256), 0, stream>>>(
        fb, mb, rowmax, N, M, D);
    finalize_kernel<<<dim3(1), dim3(1024), 0, stream>>>(pred, targ, rowmax, out, N);
}

// Round 2
// 106.675 us; speedup vs baseline: 1.2556x; 1.2556x over previous
//
#include <hip/hip_runtime.h>
#include <math.h>

typedef unsigned short u16;
typedef unsigned int u32;
typedef __attribute__((ext_vector_type(8))) __bf16 bf16x8;
typedef __attribute__((ext_vector_type(4))) float f32x4;

// ---------- helpers ----------

__device__ __forceinline__ u16 f2bf(float x) {
    __bf16 h = (__bf16)x;                 // fptrunc = round-to-nearest-even
    return __builtin_bit_cast(u16, h);
}

// order-preserving float -> uint mapping (monotonic), for atomicMax on floats
__device__ __forceinline__ u32 ordf(float f) {
    u32 u = __float_as_uint(f);
    return (u & 0x80000000u) ? ~u : (u | 0x80000000u);
}
__device__ __forceinline__ float unordf(u32 u) {
    u = (u & 0x80000000u) ? (u & 0x7FFFFFFFu) : ~u;
    return __uint_as_float(u);
}

// async global->LDS, 16B per lane (dest = wave-uniform base + lane*16)
__device__ __forceinline__ void gload_lds16(const void* gsrc, void* ldst) {
    __builtin_amdgcn_global_load_lds(
        (const __attribute__((address_space(1))) void*)gsrc,
        (__attribute__((address_space(3))) void*)ldst,
        16, 0, 0);
}

#define BARRIER do { __builtin_amdgcn_sched_barrier(0); \
                     __builtin_amdgcn_s_barrier(); \
                     __builtin_amdgcn_sched_barrier(0); } while (0)
#define LGKM0   do { asm volatile("s_waitcnt lgkmcnt(0)" ::: "memory"); \
                     __builtin_amdgcn_sched_barrier(0); } while (0)
#define VMCNT(n) do { asm volatile("s_waitcnt vmcnt(" #n ")" ::: "memory"); \
                      __builtin_amdgcn_sched_barrier(0); } while (0)

// ---------- kernel 1: normalize rows, convert to bf16; init rowmax ----------

__global__ __launch_bounds__(256) void norm_kernel(
    const float* __restrict__ feat, const float* __restrict__ memf,
    u16* __restrict__ fb, u16* __restrict__ mb, u32* __restrict__ rowmax,
    int N, int M, int D)
{
    const int lane = threadIdx.x & 63;
    const int wid  = threadIdx.x >> 6;
    const int rid  = blockIdx.x * 4 + wid;
    if (rid >= N + M) return;

    const float* src;
    u16* dst;
    if (rid < N) { src = feat + (size_t)rid * D; dst = fb + (size_t)rid * D; }
    else         { src = memf + (size_t)(rid - N) * D; dst = mb + (size_t)(rid - N) * D; }

    float4 v0 = *(const float4*)(src + lane * 8);
    float4 v1 = *(const float4*)(src + lane * 8 + 4);
    float ss = v0.x*v0.x + v0.y*v0.y + v0.z*v0.z + v0.w*v0.w
             + v1.x*v1.x + v1.y*v1.y + v1.z*v1.z + v1.w*v1.w;
    #pragma unroll
    for (int m = 1; m <= 32; m <<= 1) ss += __shfl_xor(ss, m);

    float inv = 1.0f / fmaxf(sqrtf(ss), 1e-8f);

    u16 o[8];
    o[0] = f2bf(v0.x * inv); o[1] = f2bf(v0.y * inv);
    o[2] = f2bf(v0.z * inv); o[3] = f2bf(v0.w * inv);
    o[4] = f2bf(v1.x * inv); o[5] = f2bf(v1.y * inv);
    o[6] = f2bf(v1.z * inv); o[7] = f2bf(v1.w * inv);
    *(uint4*)(dst + lane * 8) = *(const uint4*)o;

    if (rid < N && lane == 0) rowmax[rid] = 0u;   // below any real sim
}

// ---------- kernel 2: 256x256x(BK=64) 8-phase pipelined GEMM + fused row-max ----
// 8 waves (2M x 4N), per-wave output 128x64 = acc[8][4] 16x16 fragments.
// LDS 128KB: A[2][256][64] bf16 @0, B[2][256][64] @64KB. XOR-swizzled rows
// (byte ^= (row&7)<<4) via pre-swizzled global source; linear gload_lds dest.
// Half-tiles: h0=A rows 0-127, h1=A rows 128-255, h2=B rows 0-127, h3=B 128-255.
// Stage stream: tile t's h0,h1,h2 at tile (t-2) phases 1,2,3; h3 at (t-1) phase 0.
// vmcnt(6) at each phase 3 => next tile fully resident, 3 halves in flight.

#define STAGE(t, h) do { \
    const u16* gsrc_ = ((h) < 2) ? gA : gB; \
    const int base_ = (((h) < 2) ? 0 : 32768) + (((t) & 1) * 16384) + (((h) & 1) * 8192); \
    const size_t go_ = (size_t)(((h) & 1) * 128) * D + (size_t)(t) * 64; \
    gload_lds16(gsrc_ + go_,                  &L[base_ + tid * 8]); \
    gload_lds16(gsrc_ + go_ + (size_t)64 * D, &L[base_ + 4096 + tid * 8]); \
  } while (0)

#define MFMA_QUAD(RS, CS) do { \
    _Pragma("unroll") \
    for (int i_ = 0; i_ < 4; ++i_) \
      _Pragma("unroll") \
      for (int j_ = 0; j_ < 2; ++j_) \
        _Pragma("unroll") \
        for (int k_ = 0; k_ < 2; ++k_) \
          acc[(RS)*4 + i_][(CS)*2 + j_] = __builtin_amdgcn_mfma_f32_16x16x32_bf16( \
              a[RS][i_][k_], b[CS][j_][k_], acc[(RS)*4 + i_][(CS)*2 + j_], 0, 0, 0); \
  } while (0)

__global__ __launch_bounds__(512, 2) void gemm_max_kernel(
    const u16* __restrict__ fb, const u16* __restrict__ mb,
    u32* __restrict__ rowmax, int N, int M, int D)
{
    __shared__ __align__(16) u16 L[65536];   // 128 KB

    const int tid  = threadIdx.x;
    const int lane = tid & 63;
    const int wid  = tid >> 6;
    const int wr   = wid >> 2;      // 0..1
    const int wc   = wid & 3;       // 0..3
    const int l15  = lane & 15;
    const int l4   = lane >> 4;
    const int n0   = blockIdx.y * 256;
    const int m0   = blockIdx.x * 256;
    const int nt   = D >> 6;        // 8 K-tiles

    // staging: per-thread pre-swizzled global bases (row = t8, chunk = tid&7)
    const int t8   = tid >> 3;
    const int swz8 = ((tid & 7) ^ (t8 & 7)) * 8;
    const u16* gA = fb + (size_t)(n0 + t8) * D + swz8;
    const u16* gB = mb + (size_t)(m0 + t8) * D + swz8;

    // ds_read: per-thread swizzled k-offsets (full XOR incl. bit 6!)
    const int s   = (l15 & 7) << 4;
    const int oA0 = (l4 * 16) ^ s;
    const int oA1 = (64 + l4 * 16) ^ s;
    const int arow = (wr * 128 + l15) * 128;   // byte row base in A half-space
    const int brow = (wc * 64 + l15) * 128;    // byte row base in B space
    const char* Lb = (const char*)L;

    f32x4 acc[8][4] = {};
    bf16x8 a[2][4][2], b[2][2][2];

    // ---- prologue: tile0 full + tile1 h0,h1,h2 ----
    STAGE(0, 0); STAGE(0, 1); STAGE(0, 2); STAGE(0, 3);
    STAGE(1, 0); STAGE(1, 1); STAGE(1, 2);
    VMCNT(6);
    BARRIER;

    for (int u = 0; u < nt; ++u) {
        const int cb = (u & 1) * 32768;             // byte offset of current buf
        const char* Ab = Lb + cb;
        const char* Bb = Lb + 65536 + cb;
        const char* pa0 = Ab + arow + oA0;
        const char* pa1 = Ab + arow + oA1;
        const char* pb0 = Bb + brow + oA0;
        const char* pb1 = Bb + brow + oA1;

        // ---- phase 0: read all A (16) + B csub0 (4); stage h3(u+1); quad(0,0)
        #pragma unroll
        for (int i = 0; i < 8; ++i) {
            a[i >> 2][i & 3][0] = *(const bf16x8*)(pa0 + i * 2048);
            a[i >> 2][i & 3][1] = *(const bf16x8*)(pa1 + i * 2048);
        }
        #pragma unroll
        for (int j = 0; j < 2; ++j) {
            b[0][j][0] = *(const bf16x8*)(pb0 + j * 2048);
            b[0][j][1] = *(const bf16x8*)(pb1 + j * 2048);
        }
        if (u + 1 < nt) STAGE(u + 1, 3);
        BARRIER; LGKM0;
        __builtin_amdgcn_s_setprio(1);
        MFMA_QUAD(0, 0);
        __builtin_amdgcn_s_setprio(0);
        BARRIER;

        // ---- phase 1: read B csub1 (4); stage h0(u+2); quad(0,1)
        #pragma unroll
        for (int j = 0; j < 2; ++j) {
            b[1][j][0] = *(const bf16x8*)(pb0 + (2 + j) * 2048);
            b[1][j][1] = *(const bf16x8*)(pb1 + (2 + j) * 2048);
        }
        if (u + 2 < nt) STAGE(u + 2, 0);
        BARRIER; LGKM0;
        __builtin_amdgcn_s_setprio(1);
        MFMA_QUAD(0, 1);
        __builtin_amdgcn_s_setprio(0);
        BARRIER;

        // ---- phase 2: stage h1(u+2); quad(1,0)
        if (u + 2 < nt) STAGE(u + 2, 1);
        BARRIER;
        __builtin_amdgcn_s_setprio(1);
        MFMA_QUAD(1, 0);
        __builtin_amdgcn_s_setprio(0);
        BARRIER;

        // ---- phase 3: stage h2(u+2); quad(1,1); counted vmcnt
        if (u + 2 < nt) STAGE(u + 2, 2);
        BARRIER;
        __builtin_amdgcn_s_setprio(1);
        MFMA_QUAD(1, 1);
        __builtin_amdgcn_s_setprio(0);
        if (u + 2 < nt) { VMCNT(6); } else { VMCNT(0); }
        BARRIER;
    }

    // ---- epilogue: per-row max; cross-wave LDS reduce; one atomic/row ----
    float* red = (float*)L;   // [256][4]
    #pragma unroll
    for (int i = 0; i < 8; ++i) {
        #pragma unroll
        for (int rr = 0; rr < 4; ++rr) {
            float v = fmaxf(fmaxf(acc[i][0][rr], acc[i][1][rr]),
                            fmaxf(acc[i][2][rr], acc[i][3][rr]));
            v = fmaxf(v, __shfl_xor(v, 1));
            v = fmaxf(v, __shfl_xor(v, 2));
            v = fmaxf(v, __shfl_xor(v, 4));
            v = fmaxf(v, __shfl_xor(v, 8));
            if (l15 == 0) {
                int rloc = wr * 128 + i * 16 + l4 * 4 + rr;
                red[rloc * 4 + wc] = v;
            }
        }
    }
    __syncthreads();
    if (tid < 256) {
        float v = fmaxf(fmaxf(red[tid * 4 + 0], red[tid * 4 + 1]),
                        fmaxf(red[tid * 4 + 2], red[tid * 4 + 3]));
        atomicMax(&rowmax[n0 + tid], ordf(v));
    }
}

// ---------- kernel 3: BCE + novelty weight + mean ----------

__global__ __launch_bounds__(1024) void finalize_kernel(
    const float* __restrict__ pred, const float* __restrict__ targ,
    const u32* __restrict__ rowmax, float* __restrict__ out, int N)
{
    __shared__ float wsum[16];
    const int tid = threadIdx.x;
    const int lane = tid & 63;
    const int wid = tid >> 6;

    float sacc = 0.f;
    for (int i = tid; i < N; i += 1024) {
        float x = pred[i];
        float t = targ[i];
        float bl = fmaxf(x, 0.f) + log1pf(expf(-fabsf(x))) - x * t;  // softplus(x) - x*t
        float ms = unordf(rowmax[i]);
        float w = 1.0f + 2.0f * (1.0f - ms);
        sacc += bl * w;
    }
    #pragma unroll
    for (int m = 1; m <= 32; m <<= 1) sacc += __shfl_xor(sacc, m);
    if (lane == 0) wsum[wid] = sacc;
    __syncthreads();
    if (tid < 16) {
        float t = wsum[tid];
        t += __shfl_xor(t, 1);
        t += __shfl_xor(t, 2);
        t += __shfl_xor(t, 4);
        t += __shfl_xor(t, 8);
        if (tid == 0) out[0] = t / (float)N;
    }
}

// ---------- launch ----------

extern "C" void kernel_launch(void* const* d_in, const int* in_sizes, int n_in,
                              void* d_out, int out_size, void* d_ws, size_t ws_size,
                              hipStream_t stream) {
    const float* pred = (const float*)d_in[0];
    const float* targ = (const float*)d_in[1];
    const float* feat = (const float*)d_in[2];
    const float* memf = (const float*)d_in[3];
    const int N = in_sizes[0];
    const int D = in_sizes[2] / N;
    const int M = in_sizes[3] / D;
    float* out = (float*)d_out;

    u16* fb = (u16*)d_ws;                          // N*D bf16
    u16* mb = fb + (size_t)N * D;                  // M*D bf16
    u32* rowmax = (u32*)(mb + (size_t)M * D);      // N u32

    const int rows = N + M;
    norm_kernel<<<dim3((rows + 3) / 4), dim3(256), 0, stream>>>(
        feat, memf, fb, mb, rowmax, N, M, D);
    gemm_max_kernel<<<dim3(M / 256, N / 256), dim3(512), 0, stream>>>(
        fb, mb, rowmax, N, M, D);
    finalize_kernel<<<dim3(1), dim3(1024), 0, stream>>>(pred, targ, rowmax, out, N);
}

// Round 3
// 105.187 us; speedup vs baseline: 1.2734x; 1.0141x over previous
//
#include <hip/hip_runtime.h>
#include <math.h>

typedef unsigned short u16;
typedef unsigned int u32;
typedef __attribute__((ext_vector_type(8))) __bf16 bf16x8;
typedef __attribute__((ext_vector_type(4))) float f32x4;

// ---------- helpers ----------

__device__ __forceinline__ u16 f2bf(float x) {
    __bf16 h = (__bf16)x;                 // fptrunc = round-to-nearest-even
    return __builtin_bit_cast(u16, h);
}

// order-preserving float -> uint mapping (monotonic), for atomicMax on floats
__device__ __forceinline__ u32 ordf(float f) {
    u32 u = __float_as_uint(f);
    return (u & 0x80000000u) ? ~u : (u | 0x80000000u);
}
__device__ __forceinline__ float unordf(u32 u) {
    u = (u & 0x80000000u) ? (u & 0x7FFFFFFFu) : ~u;
    return __uint_as_float(u);
}

// async global->LDS, 16B per lane (dest = wave-uniform base + lane*16)
__device__ __forceinline__ void gload_lds16(const void* gsrc, void* ldst) {
    __builtin_amdgcn_global_load_lds(
        (const __attribute__((address_space(1))) void*)gsrc,
        (__attribute__((address_space(3))) void*)ldst,
        16, 0, 0);
}

#define BARRIER do { __builtin_amdgcn_sched_barrier(0); \
                     __builtin_amdgcn_s_barrier(); \
                     __builtin_amdgcn_sched_barrier(0); } while (0)
#define LGKM0   do { asm volatile("s_waitcnt lgkmcnt(0)" ::: "memory"); \
                     __builtin_amdgcn_sched_barrier(0); } while (0)
#define VMCNT(n) do { asm volatile("s_waitcnt vmcnt(" #n ")" ::: "memory"); \
                      __builtin_amdgcn_sched_barrier(0); } while (0)

// ---------- kernel 1: normalize rows, convert to bf16; init rowmax ----------

__global__ __launch_bounds__(256) void norm_kernel(
    const float* __restrict__ feat, const float* __restrict__ memf,
    u16* __restrict__ fb, u16* __restrict__ mb, u32* __restrict__ rowmax,
    int N, int M, int D)
{
    const int lane = threadIdx.x & 63;
    const int wid  = threadIdx.x >> 6;
    const int rid  = blockIdx.x * 4 + wid;
    if (rid >= N + M) return;

    const float* src;
    u16* dst;
    if (rid < N) { src = feat + (size_t)rid * D; dst = fb + (size_t)rid * D; }
    else         { src = memf + (size_t)(rid - N) * D; dst = mb + (size_t)(rid - N) * D; }

    float4 v0 = *(const float4*)(src + lane * 8);
    float4 v1 = *(const float4*)(src + lane * 8 + 4);
    float ss = v0.x*v0.x + v0.y*v0.y + v0.z*v0.z + v0.w*v0.w
             + v1.x*v1.x + v1.y*v1.y + v1.z*v1.z + v1.w*v1.w;
    #pragma unroll
    for (int m = 1; m <= 32; m <<= 1) ss += __shfl_xor(ss, m);

    float inv = 1.0f / fmaxf(sqrtf(ss), 1e-8f);

    u16 o[8];
    o[0] = f2bf(v0.x * inv); o[1] = f2bf(v0.y * inv);
    o[2] = f2bf(v0.z * inv); o[3] = f2bf(v0.w * inv);
    o[4] = f2bf(v1.x * inv); o[5] = f2bf(v1.y * inv);
    o[6] = f2bf(v1.z * inv); o[7] = f2bf(v1.w * inv);
    *(uint4*)(dst + lane * 8) = *(const uint4*)o;

    if (rid < N && lane == 0) rowmax[rid] = 0u;   // below any real sim
}

// ---------- kernel 2: 256x256x(BK=64) 8-phase pipelined GEMM + fused row-max ----
// 8 waves (2M x 4N), per-wave output 128x64 = acc[8][4] 16x16 fragments.
// LDS 128KB: A[2][256][64] bf16 @0, B[2][256][64] @64KB. XOR-swizzled rows
// (byte ^= (row&7)<<4) via pre-swizzled global source; linear gload_lds dest.
// Halves: h0=A rows 0-127 (read ONLY by wr=0 waves), h1=A rows 128-255 (wr=1),
//         h2=B rows 0-127 (wc=0,1), h3=B rows 128-255 (wc=2,3).
// Reads: a[0]+b[0] @p0 (12), b[1] @p1 (4), a[1] @p2 (8). B reads done end-p1,
// A reads done end-p2. Stage ledger (WAR-safe against those completion points):
//   p0: h3(u+1) [other buffer];  p2: h2(u+2) [after end-p1 barrier];
//   p3: h0(u+2)+h1(u+2) [after end-p2 barrier].
// vmcnt(6) at end of p3 drains exactly tile u+1's 8 loads (14 outstanding).

#define STAGE(t, h) do { \
    const u16* gsrc_ = ((h) < 2) ? gA : gB; \
    const int base_ = (((h) < 2) ? 0 : 32768) + (((t) & 1) * 16384) + (((h) & 1) * 8192); \
    const size_t go_ = (size_t)(((h) & 1) * 128) * D + (size_t)(t) * 64; \
    gload_lds16(gsrc_ + go_,                  &L[base_ + tid * 8]); \
    gload_lds16(gsrc_ + go_ + (size_t)64 * D, &L[base_ + 4096 + tid * 8]); \
  } while (0)

#define MFMA_QUAD(RS, CS) do { \
    _Pragma("unroll") \
    for (int i_ = 0; i_ < 4; ++i_) \
      _Pragma("unroll") \
      for (int j_ = 0; j_ < 2; ++j_) \
        _Pragma("unroll") \
        for (int k_ = 0; k_ < 2; ++k_) \
          acc[(RS)*4 + i_][(CS)*2 + j_] = __builtin_amdgcn_mfma_f32_16x16x32_bf16( \
              a[RS][i_][k_], b[CS][j_][k_], acc[(RS)*4 + i_][(CS)*2 + j_], 0, 0, 0); \
  } while (0)

__global__ __launch_bounds__(512, 2) void gemm_max_kernel(
    const u16* __restrict__ fb, const u16* __restrict__ mb,
    u32* __restrict__ rowmax, int N, int M, int D)
{
    __shared__ __align__(16) u16 L[65536];   // 128 KB

    const int tid  = threadIdx.x;
    const int lane = tid & 63;
    const int wid  = tid >> 6;
    const int wr   = wid >> 2;      // 0..1
    const int wc   = wid & 3;       // 0..3
    const int l15  = lane & 15;
    const int l4   = lane >> 4;
    const int n0   = blockIdx.y * 256;
    const int m0   = blockIdx.x * 256;
    const int nt   = D >> 6;        // 8 K-tiles

    // staging: per-thread pre-swizzled global bases (row = t8, chunk = tid&7)
    const int t8   = tid >> 3;
    const int swz8 = ((tid & 7) ^ (t8 & 7)) * 8;
    const u16* gA = fb + (size_t)(n0 + t8) * D + swz8;
    const u16* gB = mb + (size_t)(m0 + t8) * D + swz8;

    // ds_read: per-thread swizzled k-offsets
    const int s   = (l15 & 7) << 4;
    const int oA0 = (l4 * 16) ^ s;
    const int oA1 = (64 + l4 * 16) ^ s;
    const int arow = (wr * 128 + l15) * 128;   // byte row base in A space
    const int brow = (wc * 64 + l15) * 128;    // byte row base in B space
    const char* Lb = (const char*)L;

    f32x4 acc[8][4] = {};
    bf16x8 a[2][4][2], b[2][2][2];

    // ---- prologue: tile0 full (8 loads) + tile1 h2,h0,h1 (6 loads) ----
    STAGE(0, 0); STAGE(0, 1); STAGE(0, 2); STAGE(0, 3);
    if (nt > 1) { STAGE(1, 2); STAGE(1, 0); STAGE(1, 1); }
    VMCNT(6);
    BARRIER;

    for (int u = 0; u < nt; ++u) {
        const int cb = (u & 1) * 32768;             // byte offset of current buf
        const char* Ab = Lb + cb;
        const char* Bb = Lb + 65536 + cb;
        const char* pa0 = Ab + arow + oA0;
        const char* pa1 = Ab + arow + oA1;
        const char* pb0 = Bb + brow + oA0;
        const char* pb1 = Bb + brow + oA1;

        // ---- phase 0: read a[0] (8) + b[0] (4); stage h3(u+1); quad(0,0)
        #pragma unroll
        for (int i = 0; i < 4; ++i) {
            a[0][i][0] = *(const bf16x8*)(pa0 + i * 2048);
            a[0][i][1] = *(const bf16x8*)(pa1 + i * 2048);
        }
        #pragma unroll
        for (int j = 0; j < 2; ++j) {
            b[0][j][0] = *(const bf16x8*)(pb0 + j * 2048);
            b[0][j][1] = *(const bf16x8*)(pb1 + j * 2048);
        }
        if (u + 1 < nt) STAGE(u + 1, 3);
        BARRIER; LGKM0;
        __builtin_amdgcn_s_setprio(1);
        MFMA_QUAD(0, 0);
        __builtin_amdgcn_s_setprio(0);
        BARRIER;

        // ---- phase 1: read b[1] (4); quad(0,1)
        #pragma unroll
        for (int j = 0; j < 2; ++j) {
            b[1][j][0] = *(const bf16x8*)(pb0 + (2 + j) * 2048);
            b[1][j][1] = *(const bf16x8*)(pb1 + (2 + j) * 2048);
        }
        BARRIER; LGKM0;
        __builtin_amdgcn_s_setprio(1);
        MFMA_QUAD(0, 1);
        __builtin_amdgcn_s_setprio(0);
        BARRIER;

        // ---- phase 2: read a[1] (8); stage h2(u+2); quad(1,0)
        #pragma unroll
        for (int i = 0; i < 4; ++i) {
            a[1][i][0] = *(const bf16x8*)(pa0 + (4 + i) * 2048);
            a[1][i][1] = *(const bf16x8*)(pa1 + (4 + i) * 2048);
        }
        if (u + 2 < nt) STAGE(u + 2, 2);
        BARRIER; LGKM0;
        __builtin_amdgcn_s_setprio(1);
        MFMA_QUAD(1, 0);
        __builtin_amdgcn_s_setprio(0);
        BARRIER;

        // ---- phase 3: stage h0,h1(u+2); quad(1,1); counted vmcnt
        if (u + 2 < nt) { STAGE(u + 2, 0); STAGE(u + 2, 1); }
        BARRIER;
        __builtin_amdgcn_s_setprio(1);
        MFMA_QUAD(1, 1);
        __builtin_amdgcn_s_setprio(0);
        if (u + 2 < nt) { VMCNT(6); } else { VMCNT(0); }
        BARRIER;
    }

    // ---- epilogue: per-row max; cross-wave LDS reduce; one atomic/row ----
    float* red = (float*)L;   // [256][4]
    #pragma unroll
    for (int i = 0; i < 8; ++i) {
        #pragma unroll
        for (int rr = 0; rr < 4; ++rr) {
            float v = fmaxf(fmaxf(acc[i][0][rr], acc[i][1][rr]),
                            fmaxf(acc[i][2][rr], acc[i][3][rr]));
            v = fmaxf(v, __shfl_xor(v, 1));
            v = fmaxf(v, __shfl_xor(v, 2));
            v = fmaxf(v, __shfl_xor(v, 4));
            v = fmaxf(v, __shfl_xor(v, 8));
            if (l15 == 0) {
                int rloc = wr * 128 + i * 16 + l4 * 4 + rr;
                red[rloc * 4 + wc] = v;
            }
        }
    }
    __syncthreads();
    if (tid < 256) {
        float v = fmaxf(fmaxf(red[tid * 4 + 0], red[tid * 4 + 1]),
                        fmaxf(red[tid * 4 + 2], red[tid * 4 + 3]));
        atomicMax(&rowmax[n0 + tid], ordf(v));
    }
}

// ---------- kernel 3: BCE + novelty weight + mean ----------

__global__ __launch_bounds__(1024) void finalize_kernel(
    const float* __restrict__ pred, const float* __restrict__ targ,
    const u32* __restrict__ rowmax, float* __restrict__ out, int N)
{
    __shared__ float wsum[16];
    const int tid = threadIdx.x;
    const int lane = tid & 63;
    const int wid = tid >> 6;

    float sacc = 0.f;
    for (int i = tid; i < N; i += 1024) {
        float x = pred[i];
        float t = targ[i];
        float bl = fmaxf(x, 0.f) + log1pf(expf(-fabsf(x))) - x * t;  // softplus(x) - x*t
        float ms = unordf(rowmax[i]);
        float w = 1.0f + 2.0f * (1.0f - ms);
        sacc += bl * w;
    }
    #pragma unroll
    for (int m = 1; m <= 32; m <<= 1) sacc += __shfl_xor(sacc, m);
    if (lane == 0) wsum[wid] = sacc;
    __syncthreads();
    if (tid < 16) {
        float t = wsum[tid];
        t += __shfl_xor(t, 1);
        t += __shfl_xor(t, 2);
        t += __shfl_xor(t, 4);
        t += __shfl_xor(t, 8);
        if (tid == 0) out[0] = t / (float)N;
    }
}

// ---------- launch ----------

extern "C" void kernel_launch(void* const* d_in, const int* in_sizes, int n_in,
                              void* d_out, int out_size, void* d_ws, size_t ws_size,
                              hipStream_t stream) {
    const float* pred = (const float*)d_in[0];
    const float* targ = (const float*)d_in[1];
    const float* feat = (const float*)d_in[2];
    const float* memf = (const float*)d_in[3];
    const int N = in_sizes[0];
    const int D = in_sizes[2] / N;
    const int M = in_sizes[3] / D;
    float* out = (float*)d_out;

    u16* fb = (u16*)d_ws;                          // N*D bf16
    u16* mb = fb + (size_t)N * D;                  // M*D bf16
    u32* rowmax = (u32*)(mb + (size_t)M * D);      // N u32

    const int rows = N + M;
    norm_kernel<<<dim3((rows + 3) / 4), dim3(256), 0, stream>>>(
        feat, memf, fb, mb, rowmax, N, M, D);
    gemm_max_kernel<<<dim3(M / 256, N / 256), dim3(512), 0, stream>>>(
        fb, mb, rowmax, N, M, D);
    finalize_kernel<<<dim3(1), dim3(1024), 0, stream>>>(pred, targ, rowmax, out, N);
}